// Round 7
// baseline (210.174 us; speedup 1.0000x reference)
//
#include <hip/hip_runtime.h>
#include <stdint.h>

typedef __bf16 bf16;
typedef __bf16 bf16x8 __attribute__((ext_vector_type(8)));
typedef __bf16 bf16x4 __attribute__((ext_vector_type(4)));
typedef float f32x4 __attribute__((ext_vector_type(4)));

__device__ inline void gload_lds16(const void* g, void* l) {
  __builtin_amdgcn_global_load_lds(
      (__attribute__((address_space(1))) void*)g,
      (__attribute__((address_space(3))) void*)l, 16, 0, 0);
}

// ---------------- fused fp32 -> bf16 conversion (x + 3 weights) ----------------
__global__ __launch_bounds__(256) void cvt_all(
    const float* __restrict__ x, const float* __restrict__ wq,
    const float* __restrict__ wk, const float* __restrict__ wv,
    bf16* __restrict__ xb, bf16* __restrict__ Wb) {
  const int NX = 2097152;            // x float4 count (8192*1024/4)
  const int NW = 262144;             // per-weight float4 count (1024*1024/4)
  int i = blockIdx.x * 256 + threadIdx.x;
  const int stride = gridDim.x * 256;
  for (int p = i; p < NX + 3 * NW; p += stride) {
    const float* src; bf16* dst; int off;
    if (p < NX) { src = x; dst = xb; off = p; }
    else {
      int q = p - NX; int w = q >> 18; off = q & (NW - 1);
      src = (w == 0) ? wq : ((w == 1) ? wk : wv);
      dst = Wb + (long)w * 1048576;
    }
    float4 v = ((const float4*)src)[off];
    bf16x4 o;
    o[0] = (bf16)v.x; o[1] = (bf16)v.y; o[2] = (bf16)v.z; o[3] = (bf16)v.w;
    ((bf16x4*)dst)[off] = o;
  }
}

// =====================================================================
// gemm8: BM=256, BN=256, BK=64, 512 threads (8 waves 2Mx4N), LDS 128K,
// B-frag cache, 8-phase counted-vmcnt.  Used for QK (256 blocks, 1 round).
// MODE 2: bf16 out with scale.
// =====================================================================
template <int MODE>
__global__ __launch_bounds__(512, 2) void gemm8(
    const bf16* __restrict__ Ag, const bf16* __restrict__ Bg,
    void* __restrict__ Cg,
    long lda, long ldb, long ldc,
    long sA, long sB, long sC, int K, float scale)
{
  constexpr int BUFSZ = 65536;
  __shared__ alignas(16) char lds[2 * BUFSZ];
  const int tid = threadIdx.x;
  const int l = tid & 63;
  const int wv = tid >> 6;
  const int fr = l & 15;
  const int kch = l >> 4;
  const int m0 = blockIdx.y * 256;
  const int n0 = blockIdx.x * 256;
  const bf16* Ab = Ag + (long)blockIdx.z * sA;
  const bf16* Bb = Bg + (long)blockIdx.z * sB;

  const int wm = wv >> 2;
  const int wn = wv & 3;

  const int a_rd = fr * 128 + (((wm * 4 + kch) ^ (fr & 7)) << 4);
  const int b_rd = (wn & 1) * 8192 + fr * 128 + ((((wn >> 1) * 4 + kch) ^ (fr & 7)) << 4);

  const int se = (tid & 7) ^ ((tid >> 3) & 7);
  const int s_row = (se >> 2) * 128 + (tid >> 3);
  const int s_k = (se & 3) * 8;
  const int wb16 = (tid & 448) * 16;

  const int NT = K >> 6;
  f32x4 acc[8][4] = {};

  auto stageA = [&](int tile, int kh, int buf) {
#pragma unroll
    for (int rd = 0; rd < 2; ++rd)
      gload_lds16(Ab + (long)(m0 + s_row + rd * 64) * lda + tile * 64 + kh * 32 + s_k,
                  lds + buf * BUFSZ + kh * 16384 + rd * 8192 + wb16);
  };
  auto stageB = [&](int tile, int kh, int buf) {
#pragma unroll
    for (int rd = 0; rd < 2; ++rd)
      gload_lds16(Bb + (long)(n0 + s_row + rd * 64) * ldb + tile * 64 + kh * 32 + s_k,
                  lds + buf * BUFSZ + 32768 + kh * 16384 + rd * 8192 + wb16);
  };

  stageA(0, 0, 0); stageB(0, 0, 0); stageA(0, 1, 0); stageB(0, 1, 0);
  stageA(min(1, NT - 1), 0, 1); stageB(min(1, NT - 1), 0, 1);
  asm volatile("s_waitcnt vmcnt(4)" ::: "memory");
  __builtin_amdgcn_sched_barrier(0);
  __builtin_amdgcn_s_barrier();

  for (int t = 0; t < NT; ++t) {
    const char* bufA = lds + (t & 1) * BUFSZ;
    const char* bufB = bufA + 32768;
    const int t1 = min(t + 1, NT - 1);
    const int t2 = min(t + 2, NT - 1);
    const int nb = (t & 1) ^ 1;
    const int cur = t & 1;

    bf16x8 bfg[4], af[4];
    // P1: B(KH0) + A(KH0,MH0); stage A(t+1,k1)
    stageA(t1, 1, nb);
#pragma unroll
    for (int n = 0; n < 4; ++n) bfg[n] = *(const bf16x8*)(bufB + n * 2048 + b_rd);
#pragma unroll
    for (int m = 0; m < 4; ++m) af[m] = *(const bf16x8*)(bufA + m * 2048 + a_rd);
    __builtin_amdgcn_s_barrier();
    __builtin_amdgcn_s_setprio(1);
#pragma unroll
    for (int m = 0; m < 4; ++m)
#pragma unroll
      for (int n = 0; n < 4; ++n)
        acc[m][n] = __builtin_amdgcn_mfma_f32_16x16x32_bf16(af[m], bfg[n], acc[m][n], 0, 0, 0);
    __builtin_amdgcn_s_setprio(0);
    __builtin_amdgcn_s_barrier();
    // P2: A(KH0,MH1); B cached; stage B(t+1,k1)
    stageB(t1, 1, nb);
#pragma unroll
    for (int m = 0; m < 4; ++m) af[m] = *(const bf16x8*)(bufA + 8192 + m * 2048 + a_rd);
    __builtin_amdgcn_s_barrier();
    __builtin_amdgcn_s_setprio(1);
#pragma unroll
    for (int m = 0; m < 4; ++m)
#pragma unroll
      for (int n = 0; n < 4; ++n)
        acc[4 + m][n] = __builtin_amdgcn_mfma_f32_16x16x32_bf16(af[m], bfg[n], acc[4 + m][n], 0, 0, 0);
    __builtin_amdgcn_s_setprio(0);
    __builtin_amdgcn_s_barrier();
    // P3: B(KH1) + A(KH1,MH0); stage A(t+2,k0)
    stageA(t2, 0, cur);
#pragma unroll
    for (int n = 0; n < 4; ++n) bfg[n] = *(const bf16x8*)(bufB + 16384 + n * 2048 + b_rd);
#pragma unroll
    for (int m = 0; m < 4; ++m) af[m] = *(const bf16x8*)(bufA + 16384 + m * 2048 + a_rd);
    __builtin_amdgcn_s_barrier();
    __builtin_amdgcn_s_setprio(1);
#pragma unroll
    for (int m = 0; m < 4; ++m)
#pragma unroll
      for (int n = 0; n < 4; ++n)
        acc[m][n] = __builtin_amdgcn_mfma_f32_16x16x32_bf16(af[m], bfg[n], acc[m][n], 0, 0, 0);
    __builtin_amdgcn_s_setprio(0);
    __builtin_amdgcn_s_barrier();
    // P4: A(KH1,MH1); B cached; stage B(t+2,k0)
    stageB(t2, 0, cur);
#pragma unroll
    for (int m = 0; m < 4; ++m) af[m] = *(const bf16x8*)(bufA + 16384 + 8192 + m * 2048 + a_rd);
    __builtin_amdgcn_s_barrier();
    __builtin_amdgcn_s_setprio(1);
#pragma unroll
    for (int m = 0; m < 4; ++m)
#pragma unroll
      for (int n = 0; n < 4; ++n)
        acc[4 + m][n] = __builtin_amdgcn_mfma_f32_16x16x32_bf16(af[m], bfg[n], acc[4 + m][n], 0, 0, 0);
    __builtin_amdgcn_s_setprio(0);
    asm volatile("s_waitcnt vmcnt(4)" ::: "memory");
    __builtin_amdgcn_sched_barrier(0);
    __builtin_amdgcn_s_barrier();
  }
  asm volatile("s_waitcnt vmcnt(0)" ::: "memory");

#pragma unroll
  for (int mf = 0; mf < 8; ++mf) {
    const int row = m0 + wm * 128 + (mf >> 2) * 64 + (mf & 3) * 16 + (l >> 4) * 4;
#pragma unroll
    for (int n = 0; n < 4; ++n) {
      const int col = n0 + wn * 64 + n * 16 + fr;
      bf16* C = (bf16*)Cg + (long)blockIdx.z * sC;
#pragma unroll
      for (int r = 0; r < 4; ++r)
        C[(long)(row + r) * ldc + col] = (bf16)(acc[mf][n][r] * scale);
    }
  }
}

// =====================================================================
// gemm4: BM=256, BN=128, BK=64, 256 threads (4 waves 2Mx2N), wave-tile
// 128x64 WITH B-frag cache.  LDS 96K (A 2x16K kh-regions + B 2x8K),
// 4-phase counted vmcnt(6).  A-side layout == gemm8's A (0 conflicts
// verified), B-side == gemm2h's B (0 conflicts verified).
// Per wave per K-tile: 16 A-reads + 8 B-reads, 64 MFMA  (QK's ratio).
// MODE 0: proj epilogue (col<2048 -> bf16 Cg ld2048; else V^T -> C2g)
// MODE 1: fp32 out with scale.
// =====================================================================
template <int MODE>
__global__ __launch_bounds__(256, 1) void gemm4(
    const bf16* __restrict__ Ag, const bf16* __restrict__ Bg,
    void* __restrict__ Cg, void* __restrict__ C2g,
    long lda, long ldb, long ldc,
    long sA, long sB, long sC, int K, float scale)
{
  constexpr int BUFSZ = 49152;  // A: kh*16384 (32K), B: 32768 + kh*8192 (16K)
  __shared__ alignas(16) char lds[2 * BUFSZ];
  const int tid = threadIdx.x;       // 0..255
  const int l = tid & 63;
  const int wv = tid >> 6;           // 0..3
  const int wm = wv >> 1, wn = wv & 1;
  const int fr = l & 15;
  const int kch = l >> 4;
  const int m0 = blockIdx.y * 256;
  const int n0 = blockIdx.x * 128;
  const bf16* Ab = Ag + (long)blockIdx.z * sA;
  const bf16* Bb = Bg + (long)blockIdx.z * sB;

  // fragment-read byte offsets (A: +kh*16384 +mh*8192 +m*2048;
  //                             B: +32768 +kh*8192 +n*2048)
  const int a_rd = fr * 128 + (((wm * 4 + kch) ^ (fr & 7)) << 4);
  const int b_rd = fr * 128 + (((wn * 4 + kch) ^ (fr & 7)) << 4);

  // staging (inverse swizzle), linear gload_lds dest
  const int se = (tid & 7) ^ ((tid >> 3) & 7);
  const int s_rowA = (se >> 2) * 128 + (tid >> 3);  // + rd*32, rd=0..3
  const int s_rowB = (se >> 2) * 64 + (tid >> 3);   // + rd*32, rd=0..1
  const int s_k = (se & 3) * 8;
  const int wb16 = (tid >> 6) * 1024;               // wave-uniform dest base

  const int NT = K >> 6;
  f32x4 acc[8][4] = {};

  auto stageA = [&](int tile, int kh, int buf) {
#pragma unroll
    for (int rd = 0; rd < 4; ++rd)
      gload_lds16(Ab + (long)(m0 + s_rowA + rd * 32) * lda + tile * 64 + kh * 32 + s_k,
                  lds + buf * BUFSZ + kh * 16384 + rd * 4096 + wb16);
  };
  auto stageB = [&](int tile, int kh, int buf) {
#pragma unroll
    for (int rd = 0; rd < 2; ++rd)
      gload_lds16(Bb + (long)(n0 + s_rowB + rd * 32) * ldb + tile * 64 + kh * 32 + s_k,
                  lds + buf * BUFSZ + 32768 + kh * 8192 + rd * 4096 + wb16);
  };

  // prologue: tile0 fully -> buf0 (12 loads), tile1 kh0 -> buf1 (6)
  stageA(0, 0, 0); stageB(0, 0, 0); stageA(0, 1, 0); stageB(0, 1, 0);
  stageA(min(1, NT - 1), 0, 1); stageB(min(1, NT - 1), 0, 1);
  asm volatile("s_waitcnt vmcnt(6)" ::: "memory");
  __builtin_amdgcn_sched_barrier(0);
  __builtin_amdgcn_s_barrier();

  for (int t = 0; t < NT; ++t) {
    const char* bufA = lds + (t & 1) * BUFSZ;
    const char* bufB = bufA + 32768;
    const int t1 = min(t + 1, NT - 1);
    const int t2 = min(t + 2, NT - 1);
    const int nb = (t & 1) ^ 1;
    const int cur = t & 1;

    bf16x8 bfg[4], af[4];
    // P1: B(kh0) + A(kh0,mh0); stage A(t+1,kh1)
    stageA(t1, 1, nb);
#pragma unroll
    for (int n = 0; n < 4; ++n) bfg[n] = *(const bf16x8*)(bufB + n * 2048 + b_rd);
#pragma unroll
    for (int m = 0; m < 4; ++m) af[m] = *(const bf16x8*)(bufA + m * 2048 + a_rd);
    __builtin_amdgcn_s_barrier();
    __builtin_amdgcn_s_setprio(1);
#pragma unroll
    for (int m = 0; m < 4; ++m)
#pragma unroll
      for (int n = 0; n < 4; ++n)
        acc[m][n] = __builtin_amdgcn_mfma_f32_16x16x32_bf16(af[m], bfg[n], acc[m][n], 0, 0, 0);
    __builtin_amdgcn_s_setprio(0);
    __builtin_amdgcn_s_barrier();
    // P2: A(kh0,mh1); B cached; stage B(t+1,kh1)
    stageB(t1, 1, nb);
#pragma unroll
    for (int m = 0; m < 4; ++m) af[m] = *(const bf16x8*)(bufA + 8192 + m * 2048 + a_rd);
    __builtin_amdgcn_s_barrier();
    __builtin_amdgcn_s_setprio(1);
#pragma unroll
    for (int m = 0; m < 4; ++m)
#pragma unroll
      for (int n = 0; n < 4; ++n)
        acc[4 + m][n] = __builtin_amdgcn_mfma_f32_16x16x32_bf16(af[m], bfg[n], acc[4 + m][n], 0, 0, 0);
    __builtin_amdgcn_s_setprio(0);
    __builtin_amdgcn_s_barrier();
    // P3: B(kh1) + A(kh1,mh0); stage A(t+2,kh0)
    stageA(t2, 0, cur);
#pragma unroll
    for (int n = 0; n < 4; ++n) bfg[n] = *(const bf16x8*)(bufB + 8192 + n * 2048 + b_rd);
#pragma unroll
    for (int m = 0; m < 4; ++m) af[m] = *(const bf16x8*)(bufA + 16384 + m * 2048 + a_rd);
    __builtin_amdgcn_s_barrier();
    __builtin_amdgcn_s_setprio(1);
#pragma unroll
    for (int m = 0; m < 4; ++m)
#pragma unroll
      for (int n = 0; n < 4; ++n)
        acc[m][n] = __builtin_amdgcn_mfma_f32_16x16x32_bf16(af[m], bfg[n], acc[m][n], 0, 0, 0);
    __builtin_amdgcn_s_setprio(0);
    __builtin_amdgcn_s_barrier();
    // P4: A(kh1,mh1); B cached; stage B(t+2,kh0)
    stageB(t2, 0, cur);
#pragma unroll
    for (int m = 0; m < 4; ++m) af[m] = *(const bf16x8*)(bufA + 16384 + 8192 + m * 2048 + a_rd);
    __builtin_amdgcn_s_barrier();
    __builtin_amdgcn_s_setprio(1);
#pragma unroll
    for (int m = 0; m < 4; ++m)
#pragma unroll
      for (int n = 0; n < 4; ++n)
        acc[4 + m][n] = __builtin_amdgcn_mfma_f32_16x16x32_bf16(af[m], bfg[n], acc[4 + m][n], 0, 0, 0);
    __builtin_amdgcn_s_setprio(0);
    asm volatile("s_waitcnt vmcnt(6)" ::: "memory");
    __builtin_amdgcn_sched_barrier(0);
    __builtin_amdgcn_s_barrier();
  }
  asm volatile("s_waitcnt vmcnt(0)" ::: "memory");

  // epilogue: C/D layout col=lane&15, row=(lane>>4)*4+reg
#pragma unroll
  for (int mf = 0; mf < 8; ++mf) {
    const int row = m0 + wm * 128 + (mf >> 2) * 64 + (mf & 3) * 16 + (l >> 4) * 4;
#pragma unroll
    for (int n = 0; n < 4; ++n) {
      const int col = n0 + wn * 64 + n * 16 + fr;
      if constexpr (MODE == 0) {
        if (col < 2048) {
          bf16* C = (bf16*)Cg;
#pragma unroll
          for (int r = 0; r < 4; ++r)
            C[(long)(row + r) * 2048 + col] = (bf16)acc[mf][n][r];
        } else {
          bf16* Vt = (bf16*)C2g;
          const int d = col - 2048;
          const int b = row >> 11;
          const int s = row & 2047;
          bf16x4 pk;
#pragma unroll
          for (int r = 0; r < 4; ++r) pk[r] = (bf16)acc[mf][n][r];
          *(bf16x4*)(Vt + (long)b * 2097152 + (long)d * 2048 + s) = pk;
        }
      } else {
        float* C = (float*)Cg + (long)blockIdx.z * sC;
#pragma unroll
        for (int r = 0; r < 4; ++r)
          C[(long)(row + r) * ldc + col] = acc[mf][n][r] * scale;
      }
    }
  }
}

// ---------------- row softmax: bf16 scores -> bf16 P ----------------
__global__ __launch_bounds__(256) void softmax_k(const bf16* __restrict__ Sm,
                                                 bf16* __restrict__ P, int cols) {
  __shared__ float red[8];
  const long row = blockIdx.x;
  const bf16* sr = Sm + row * (long)cols;
  bf16* pr = P + row * (long)cols;
  const int t = threadIdx.x;
  bf16x8 v = *(const bf16x8*)(sr + t * 8);
  float e[8];
#pragma unroll
  for (int j = 0; j < 8; ++j) e[j] = (float)v[j];
  float m = e[0];
#pragma unroll
  for (int j = 1; j < 8; ++j) m = fmaxf(m, e[j]);
#pragma unroll
  for (int o = 32; o; o >>= 1) m = fmaxf(m, __shfl_xor(m, o));
  if ((t & 63) == 0) red[t >> 6] = m;
  __syncthreads();
  m = fmaxf(fmaxf(red[0], red[1]), fmaxf(red[2], red[3]));
  float s = 0.f;
#pragma unroll
  for (int j = 0; j < 8; ++j) { e[j] = __expf(e[j] - m); s += e[j]; }
#pragma unroll
  for (int o = 32; o; o >>= 1) s += __shfl_xor(s, o);
  if ((t & 63) == 0) red[4 + (t >> 6)] = s;
  __syncthreads();
  s = red[4] + red[5] + red[6] + red[7];
  const float inv = 1.0f / s;
  bf16x8 o8;
#pragma unroll
  for (int j = 0; j < 8; ++j) o8[j] = (bf16)(e[j] * inv);
  *(bf16x8*)(pr + t * 8) = o8;
}

extern "C" void kernel_launch(void* const* d_in, const int* in_sizes, int n_in,
                              void* d_out, int out_size, void* d_ws, size_t ws_size,
                              hipStream_t stream) {
  const float* x  = (const float*)d_in[0];
  const float* Wq = (const float*)d_in[1];
  const float* Wk = (const float*)d_in[2];
  const float* Wv = (const float*)d_in[3];
  float* out = (float*)d_out;

  // workspace (117.44 MB):
  //  [0, 33.55M)        QKbuf bf16 [8192][2048]  -> later P (softmax out)
  //  [33.55M, 50.33M)   Vt bf16 [4][1024][2048]  (written by proj epilogue)
  //  [50.33M, 83.89M)   scores bf16 [4][2048][2048]
  //     (pre-QK this region holds xb @50.33M (16.78M), Wb @67.11M (6.29M))
  char* ws = (char*)d_ws;
  bf16* QKbuf = (bf16*)(ws);
  bf16* P     = (bf16*)(ws);
  bf16* Vt    = (bf16*)(ws + 33554432);
  bf16* scb   = (bf16*)(ws + 50331648);
  bf16* xb    = (bf16*)(ws + 50331648);
  bf16* Wb    = (bf16*)(ws + 67108864);

  dim3 b256(256, 1, 1), b512(512, 1, 1);

  // 1) fused conversion: x -> xb, weights -> Wb packed [3][1024][1024]
  cvt_all<<<2048, b256, 0, stream>>>(x, Wq, Wk, Wv, xb, Wb);

  // 2) fused QKV proj (gemm4: 768 blocks = 3 exact rounds at 1 block/CU):
  //    [8192,3072] = xb @ Wb^T; Q/K packed -> QKbuf, V^T -> Vt
  gemm4<0><<<dim3(24, 32, 1), b256, 0, stream>>>(
      xb, Wb, QKbuf, Vt, 1024, 1024, 2048, 0, 0, 0, 1024, 1.f);

  // 3) scores = Q @ K^T / 32 -> bf16 (gemm8; 256 blocks = 1 round)
  gemm8<2><<<dim3(8, 8, 4), b512, 0, stream>>>(
      QKbuf, QKbuf + 1024, scb, 2048, 2048, 2048,
      4194304, 4194304, 4194304, 1024, 0.03125f);

  // 4) softmax rows (bf16 in) -> bf16 P (overwrites dead QKbuf)
  softmax_k<<<8192, b256, 0, stream>>>(scb, P, 2048);

  // 5) out = P @ Vt^T (gemm4: 256 blocks = 1 round)
  gemm4<1><<<dim3(8, 8, 4), b256, 0, stream>>>(
      P, Vt, out, nullptr, 2048, 2048, 1024,
      4194304, 2097152, 2097152, 2048, 1.f);
}

// Round 8
// 167.584 us; speedup vs baseline: 1.2541x; 1.2541x over previous
//
#include <hip/hip_runtime.h>
#include <stdint.h>

typedef __bf16 bf16;
typedef __bf16 bf16x8 __attribute__((ext_vector_type(8)));
typedef __bf16 bf16x4 __attribute__((ext_vector_type(4)));
typedef float f32x4 __attribute__((ext_vector_type(4)));

__device__ inline void gload_lds16(const void* g, void* l) {
  __builtin_amdgcn_global_load_lds(
      (__attribute__((address_space(1))) void*)g,
      (__attribute__((address_space(3))) void*)l, 16, 0, 0);
}

// ---------------- fused fp32 -> bf16 conversion (x + 3 weights) ----------------
__global__ __launch_bounds__(256) void cvt_all(
    const float* __restrict__ x, const float* __restrict__ wq,
    const float* __restrict__ wk, const float* __restrict__ wv,
    bf16* __restrict__ xb, bf16* __restrict__ Wb) {
  const int NX = 2097152;
  const int NW = 262144;
  int i = blockIdx.x * 256 + threadIdx.x;
  const int stride = gridDim.x * 256;
  for (int p = i; p < NX + 3 * NW; p += stride) {
    const float* src; bf16* dst; int off;
    if (p < NX) { src = x; dst = xb; off = p; }
    else {
      int q = p - NX; int w = q >> 18; off = q & (NW - 1);
      src = (w == 0) ? wq : ((w == 1) ? wk : wv);
      dst = Wb + (long)w * 1048576;
    }
    float4 v = ((const float4*)src)[off];
    bf16x4 o;
    o[0] = (bf16)v.x; o[1] = (bf16)v.y; o[2] = (bf16)v.z; o[3] = (bf16)v.w;
    ((bf16x4*)dst)[off] = o;
  }
}

// =====================================================================
// projT: transposed QKV projection  C'[wrow, xrow] = W·x^T.
// M=3072 (W rows), N=8192 (x rows) -> grid 8y x 32x = 256 blocks EXACT.
// BM=384, BN=256, BK=32, 512 threads (8 waves 2Mx4N), wave-tile 192x64
// with B-frag cache across 3 MH phases.  LDS 2 x (A 24K + B 16K) = 80K.
// Counted vmcnt(3); staging honors sub-region liveness (verified algebra).
// Epilogue scatters: wrow<2048 -> QKbuf[xrow][wrow] (bf16x4 along wrow);
//                    wrow>=2048 -> Vt[b][wrow-2048][xrow&2047].
// =====================================================================
__global__ __launch_bounds__(512, 2) void projT(
    const bf16* __restrict__ Wg, const bf16* __restrict__ Xg,
    bf16* __restrict__ QKbuf, bf16* __restrict__ Vt)
{
  constexpr int BUFSZ = 40960;   // A 24576 + B 16384
  __shared__ alignas(16) char lds[2 * BUFSZ];
  const int tid = threadIdx.x;
  const int l = tid & 63;
  const int wv = tid >> 6;
  const int wm = wv >> 2;        // 0..1
  const int wn = wv & 3;         // 0..3
  const int fr = l & 15;
  const int kch = l >> 4;
  const int m0 = blockIdx.y * 384;   // W-row base
  const int n0 = blockIdx.x * 256;   // x-row base

  // fragment-read byte offsets (within A region: +MH*8192 +m*2048;
  //                             within B region: base 24576)
  const int a_rd = fr * 128 + (((wm * 4 + kch) ^ (fr & 7)) << 4);
  const int b_rd = 24576 + (wn & 1) * 8192 + fr * 128 + ((((wn >> 1) * 4 + kch) ^ (fr & 7)) << 4);

  // staging (inverse swizzle), linear gload_lds dest (8K per call)
  const int se = (tid & 7) ^ ((tid >> 3) & 7);
  const int s_rowA = (se >> 2) * 192 + (tid >> 3);   // + rd*64, rd=0..2
  const int s_rowB = (se >> 2) * 128 + (tid >> 3);   // + rd*64, rd=0..1
  const int s_k = (se & 3) * 8;
  const int wb16 = (tid & 448) * 16;

  const int NT = 32;  // K=1024 / 32
  f32x4 acc[12][4] = {};

  auto stageA = [&](int tile, int buf, int rd) {
    gload_lds16(Wg + (long)(m0 + s_rowA + rd * 64) * 1024 + tile * 32 + s_k,
                lds + buf * BUFSZ + rd * 8192 + wb16);
  };
  auto stageB = [&](int tile, int buf, int rd) {
    gload_lds16(Xg + (long)(n0 + s_rowB + rd * 64) * 1024 + tile * 32 + s_k,
                lds + buf * BUFSZ + 24576 + rd * 8192 + wb16);
  };

  // prologue: tile0 full (5), tile1 partial {A0,B0,A1} (3)
  stageA(0, 0, 0); stageB(0, 0, 0); stageA(0, 0, 1); stageB(0, 0, 1); stageA(0, 0, 2);
  stageA(1, 1, 0); stageB(1, 1, 0); stageA(1, 1, 1);
  asm volatile("s_waitcnt vmcnt(3)" ::: "memory");
  __builtin_amdgcn_sched_barrier(0);
  __builtin_amdgcn_s_barrier();

  for (int t = 0; t < NT; ++t) {
    const char* buf = lds + (t & 1) * BUFSZ;
    const int t1 = min(t + 1, NT - 1);
    const int t2 = min(t + 2, NT - 1);
    const int nb = (t & 1) ^ 1;
    const int cur = t & 1;

    bf16x8 bfg[4], af[4];
    // P1: finish t+1 staging {A r2, B r1}; read B(all) + A MH0
    stageA(t1, nb, 2); stageB(t1, nb, 1);
#pragma unroll
    for (int n = 0; n < 4; ++n) bfg[n] = *(const bf16x8*)(buf + n * 2048 + b_rd);
#pragma unroll
    for (int m = 0; m < 4; ++m) af[m] = *(const bf16x8*)(buf + m * 2048 + a_rd);
    __builtin_amdgcn_s_barrier();
    __builtin_amdgcn_s_setprio(1);
#pragma unroll
    for (int m = 0; m < 4; ++m)
#pragma unroll
      for (int n = 0; n < 4; ++n)
        acc[m][n] = __builtin_amdgcn_mfma_f32_16x16x32_bf16(af[m], bfg[n], acc[m][n], 0, 0, 0);
    __builtin_amdgcn_s_setprio(0);
    __builtin_amdgcn_s_barrier();
    // P2: stage t+2 {A r0 (cur MH0 free), B r0 (cur B free)}; read A MH1
    stageA(t2, cur, 0); stageB(t2, cur, 0);
#pragma unroll
    for (int m = 0; m < 4; ++m) af[m] = *(const bf16x8*)(buf + 8192 + m * 2048 + a_rd);
    __builtin_amdgcn_s_barrier();
    __builtin_amdgcn_s_setprio(1);
#pragma unroll
    for (int m = 0; m < 4; ++m)
#pragma unroll
      for (int n = 0; n < 4; ++n)
        acc[4 + m][n] = __builtin_amdgcn_mfma_f32_16x16x32_bf16(af[m], bfg[n], acc[4 + m][n], 0, 0, 0);
    __builtin_amdgcn_s_setprio(0);
    __builtin_amdgcn_s_barrier();
    // P3: stage t+2 {A r1 (cur MH1 free)}; read A MH2
    stageA(t2, cur, 1);
#pragma unroll
    for (int m = 0; m < 4; ++m) af[m] = *(const bf16x8*)(buf + 16384 + m * 2048 + a_rd);
    __builtin_amdgcn_s_barrier();
    __builtin_amdgcn_s_setprio(1);
#pragma unroll
    for (int m = 0; m < 4; ++m)
#pragma unroll
      for (int n = 0; n < 4; ++n)
        acc[8 + m][n] = __builtin_amdgcn_mfma_f32_16x16x32_bf16(af[m], bfg[n], acc[8 + m][n], 0, 0, 0);
    __builtin_amdgcn_s_setprio(0);
    asm volatile("s_waitcnt vmcnt(3)" ::: "memory");
    __builtin_amdgcn_sched_barrier(0);
    __builtin_amdgcn_s_barrier();
  }
  asm volatile("s_waitcnt vmcnt(0)" ::: "memory");

  // epilogue: acc row = W-row (output col), acc col = x-row (output row)
#pragma unroll
  for (int mf = 0; mf < 12; ++mf) {
    const int wrow = m0 + wm * 192 + (mf >> 2) * 64 + (mf & 3) * 16 + (l >> 4) * 4;
#pragma unroll
    for (int n = 0; n < 4; ++n) {
      const int xrow = n0 + wn * 64 + n * 16 + fr;
      if (wrow < 2048) {
        bf16x4 pk;
#pragma unroll
        for (int r = 0; r < 4; ++r) pk[r] = (bf16)acc[mf][n][r];
        *(bf16x4*)(QKbuf + (long)xrow * 2048 + wrow) = pk;
      } else {
        const int b = xrow >> 11;
        const int s = xrow & 2047;
#pragma unroll
        for (int r = 0; r < 4; ++r)
          Vt[(long)b * 2097152 + (long)(wrow - 2048 + r) * 2048 + s] = (bf16)acc[mf][n][r];
      }
    }
  }
}

// =====================================================================
// gemm8: BM=256, BN=256, BK=64, 512 threads (8 waves 2Mx4N), LDS 128K,
// B-frag cache, 8-phase counted-vmcnt.  Used for QK (256 blocks, 1 round).
// bf16 out with scale.
// =====================================================================
__global__ __launch_bounds__(512, 2) void gemm8(
    const bf16* __restrict__ Ag, const bf16* __restrict__ Bg,
    bf16* __restrict__ Cg,
    long lda, long ldb, long ldc,
    long sA, long sB, long sC, int K, float scale)
{
  constexpr int BUFSZ = 65536;
  __shared__ alignas(16) char lds[2 * BUFSZ];
  const int tid = threadIdx.x;
  const int l = tid & 63;
  const int wv = tid >> 6;
  const int fr = l & 15;
  const int kch = l >> 4;
  const int m0 = blockIdx.y * 256;
  const int n0 = blockIdx.x * 256;
  const bf16* Ab = Ag + (long)blockIdx.z * sA;
  const bf16* Bb = Bg + (long)blockIdx.z * sB;

  const int wm = wv >> 2;
  const int wn = wv & 3;

  const int a_rd = fr * 128 + (((wm * 4 + kch) ^ (fr & 7)) << 4);
  const int b_rd = (wn & 1) * 8192 + fr * 128 + ((((wn >> 1) * 4 + kch) ^ (fr & 7)) << 4);

  const int se = (tid & 7) ^ ((tid >> 3) & 7);
  const int s_row = (se >> 2) * 128 + (tid >> 3);
  const int s_k = (se & 3) * 8;
  const int wb16 = (tid & 448) * 16;

  const int NT = K >> 6;
  f32x4 acc[8][4] = {};

  auto stageA = [&](int tile, int kh, int buf) {
#pragma unroll
    for (int rd = 0; rd < 2; ++rd)
      gload_lds16(Ab + (long)(m0 + s_row + rd * 64) * lda + tile * 64 + kh * 32 + s_k,
                  lds + buf * BUFSZ + kh * 16384 + rd * 8192 + wb16);
  };
  auto stageB = [&](int tile, int kh, int buf) {
#pragma unroll
    for (int rd = 0; rd < 2; ++rd)
      gload_lds16(Bb + (long)(n0 + s_row + rd * 64) * ldb + tile * 64 + kh * 32 + s_k,
                  lds + buf * BUFSZ + 32768 + kh * 16384 + rd * 8192 + wb16);
  };

  stageA(0, 0, 0); stageB(0, 0, 0); stageA(0, 1, 0); stageB(0, 1, 0);
  stageA(min(1, NT - 1), 0, 1); stageB(min(1, NT - 1), 0, 1);
  asm volatile("s_waitcnt vmcnt(4)" ::: "memory");
  __builtin_amdgcn_sched_barrier(0);
  __builtin_amdgcn_s_barrier();

  for (int t = 0; t < NT; ++t) {
    const char* bufA = lds + (t & 1) * BUFSZ;
    const char* bufB = bufA + 32768;
    const int t1 = min(t + 1, NT - 1);
    const int t2 = min(t + 2, NT - 1);
    const int nb = (t & 1) ^ 1;
    const int cur = t & 1;

    bf16x8 bfg[4], af[4];
    // P1
    stageA(t1, 1, nb);
#pragma unroll
    for (int n = 0; n < 4; ++n) bfg[n] = *(const bf16x8*)(bufB + n * 2048 + b_rd);
#pragma unroll
    for (int m = 0; m < 4; ++m) af[m] = *(const bf16x8*)(bufA + m * 2048 + a_rd);
    __builtin_amdgcn_s_barrier();
    __builtin_amdgcn_s_setprio(1);
#pragma unroll
    for (int m = 0; m < 4; ++m)
#pragma unroll
      for (int n = 0; n < 4; ++n)
        acc[m][n] = __builtin_amdgcn_mfma_f32_16x16x32_bf16(af[m], bfg[n], acc[m][n], 0, 0, 0);
    __builtin_amdgcn_s_setprio(0);
    __builtin_amdgcn_s_barrier();
    // P2
    stageB(t1, 1, nb);
#pragma unroll
    for (int m = 0; m < 4; ++m) af[m] = *(const bf16x8*)(bufA + 8192 + m * 2048 + a_rd);
    __builtin_amdgcn_s_barrier();
    __builtin_amdgcn_s_setprio(1);
#pragma unroll
    for (int m = 0; m < 4; ++m)
#pragma unroll
      for (int n = 0; n < 4; ++n)
        acc[4 + m][n] = __builtin_amdgcn_mfma_f32_16x16x32_bf16(af[m], bfg[n], acc[4 + m][n], 0, 0, 0);
    __builtin_amdgcn_s_setprio(0);
    __builtin_amdgcn_s_barrier();
    // P3
    stageA(t2, 0, cur);
#pragma unroll
    for (int n = 0; n < 4; ++n) bfg[n] = *(const bf16x8*)(bufB + 16384 + n * 2048 + b_rd);
#pragma unroll
    for (int m = 0; m < 4; ++m) af[m] = *(const bf16x8*)(bufA + 16384 + m * 2048 + a_rd);
    __builtin_amdgcn_s_barrier();
    __builtin_amdgcn_s_setprio(1);
#pragma unroll
    for (int m = 0; m < 4; ++m)
#pragma unroll
      for (int n = 0; n < 4; ++n)
        acc[m][n] = __builtin_amdgcn_mfma_f32_16x16x32_bf16(af[m], bfg[n], acc[m][n], 0, 0, 0);
    __builtin_amdgcn_s_setprio(0);
    __builtin_amdgcn_s_barrier();
    // P4
    stageB(t2, 0, cur);
#pragma unroll
    for (int m = 0; m < 4; ++m) af[m] = *(const bf16x8*)(bufA + 16384 + 8192 + m * 2048 + a_rd);
    __builtin_amdgcn_s_barrier();
    __builtin_amdgcn_s_setprio(1);
#pragma unroll
    for (int m = 0; m < 4; ++m)
#pragma unroll
      for (int n = 0; n < 4; ++n)
        acc[4 + m][n] = __builtin_amdgcn_mfma_f32_16x16x32_bf16(af[m], bfg[n], acc[4 + m][n], 0, 0, 0);
    __builtin_amdgcn_s_setprio(0);
    asm volatile("s_waitcnt vmcnt(4)" ::: "memory");
    __builtin_amdgcn_sched_barrier(0);
    __builtin_amdgcn_s_barrier();
  }
  asm volatile("s_waitcnt vmcnt(0)" ::: "memory");

#pragma unroll
  for (int mf = 0; mf < 8; ++mf) {
    const int row = m0 + wm * 128 + (mf >> 2) * 64 + (mf & 3) * 16 + (l >> 4) * 4;
#pragma unroll
    for (int n = 0; n < 4; ++n) {
      const int col = n0 + wn * 64 + n * 16 + fr;
      bf16* C = Cg + (long)blockIdx.z * sC;
#pragma unroll
      for (int r = 0; r < 4; ++r)
        C[(long)(row + r) * ldc + col] = (bf16)(acc[mf][n][r] * scale);
    }
  }
}

// =====================================================================
// gemm2h: BM=128, BN=128, BK=64, 256 threads (4 waves 2Mx2N), LDS 64K.
// Used for PV (512 blocks at 2/CU).  fp32 out.
// =====================================================================
__global__ __launch_bounds__(256, 2) void gemm2h(
    const bf16* __restrict__ Ag, const bf16* __restrict__ Bg,
    float* __restrict__ Cg,
    long lda, long ldb, long ldc,
    long sA, long sB, long sC, int K)
{
  constexpr int BUFSZ = 32768;
  __shared__ alignas(16) char lds[2 * BUFSZ];
  const int tid = threadIdx.x;
  const int l = tid & 63;
  const int wv = tid >> 6;
  const int wm = wv >> 1, wn = wv & 1;
  const int fr = l & 15;
  const int kch = l >> 4;
  const int m0 = blockIdx.y * 128;
  const int n0 = blockIdx.x * 128;
  const bf16* Ab = Ag + (long)blockIdx.z * sA;
  const bf16* Bb = Bg + (long)blockIdx.z * sB;

  const int a_rd = fr * 128 + (((wm * 4 + kch) ^ (fr & 7)) << 4);
  const int b_rd = fr * 128 + (((wn * 4 + kch) ^ (fr & 7)) << 4);

  const int se = (tid & 7) ^ ((tid >> 3) & 7);
  const int s_row = (se >> 2) * 64 + (tid >> 3);
  const int s_k = (se & 3) * 8;
  const int wb16 = (tid >> 6) * 1024;

  const int NT = K >> 6;
  f32x4 acc[4][4] = {};

  auto stageA = [&](int tile, int kh, int buf) {
#pragma unroll
    for (int rd = 0; rd < 2; ++rd)
      gload_lds16(Ab + (long)(m0 + s_row + rd * 32) * lda + tile * 64 + kh * 32 + s_k,
                  lds + buf * BUFSZ + kh * 8192 + rd * 4096 + wb16);
  };
  auto stageB = [&](int tile, int kh, int buf) {
#pragma unroll
    for (int rd = 0; rd < 2; ++rd)
      gload_lds16(Bb + (long)(n0 + s_row + rd * 32) * ldb + tile * 64 + kh * 32 + s_k,
                  lds + buf * BUFSZ + 16384 + kh * 8192 + rd * 4096 + wb16);
  };

  stageA(0, 0, 0); stageB(0, 0, 0); stageA(0, 1, 0); stageB(0, 1, 0);
  stageA(min(1, NT - 1), 0, 1); stageB(min(1, NT - 1), 0, 1);
  asm volatile("s_waitcnt vmcnt(4)" ::: "memory");
  __builtin_amdgcn_sched_barrier(0);
  __builtin_amdgcn_s_barrier();

  for (int t = 0; t < NT; ++t) {
    const char* bufA = lds + (t & 1) * BUFSZ;
    const char* bufB = bufA + 16384;
    const int t1 = min(t + 1, NT - 1);
    const int t2 = min(t + 2, NT - 1);
    const int nb = (t & 1) ^ 1;
    const int cur = t & 1;

    bf16x8 bfg[4], af[4];
    stageA(t1, 1, nb); stageB(t1, 1, nb);
#pragma unroll
    for (int n = 0; n < 4; ++n) bfg[n] = *(const bf16x8*)(bufB + n * 2048 + b_rd);
#pragma unroll
    for (int m = 0; m < 4; ++m) af[m] = *(const bf16x8*)(bufA + m * 2048 + a_rd);
    __builtin_amdgcn_s_barrier();
    __builtin_amdgcn_s_setprio(1);
#pragma unroll
    for (int m = 0; m < 4; ++m)
#pragma unroll
      for (int n = 0; n < 4; ++n)
        acc[m][n] = __builtin_amdgcn_mfma_f32_16x16x32_bf16(af[m], bfg[n], acc[m][n], 0, 0, 0);
    __builtin_amdgcn_s_setprio(0);
    __builtin_amdgcn_s_barrier();
    stageA(t2, 0, cur); stageB(t2, 0, cur);
#pragma unroll
    for (int n = 0; n < 4; ++n) bfg[n] = *(const bf16x8*)(bufB + 8192 + n * 2048 + b_rd);
#pragma unroll
    for (int m = 0; m < 4; ++m) af[m] = *(const bf16x8*)(bufA + 8192 + m * 2048 + a_rd);
    __builtin_amdgcn_s_barrier();
    __builtin_amdgcn_s_setprio(1);
#pragma unroll
    for (int m = 0; m < 4; ++m)
#pragma unroll
      for (int n = 0; n < 4; ++n)
        acc[m][n] = __builtin_amdgcn_mfma_f32_16x16x32_bf16(af[m], bfg[n], acc[m][n], 0, 0, 0);
    __builtin_amdgcn_s_setprio(0);
    asm volatile("s_waitcnt vmcnt(4)" ::: "memory");
    __builtin_amdgcn_sched_barrier(0);
    __builtin_amdgcn_s_barrier();
  }
  asm volatile("s_waitcnt vmcnt(0)" ::: "memory");

#pragma unroll
  for (int mf = 0; mf < 4; ++mf) {
    const int row = m0 + wm * 64 + mf * 16 + (l >> 4) * 4;
#pragma unroll
    for (int n = 0; n < 4; ++n) {
      const int col = n0 + wn * 64 + n * 16 + fr;
      float* C = Cg + (long)blockIdx.z * sC;
#pragma unroll
      for (int r = 0; r < 4; ++r)
        C[(long)(row + r) * ldc + col] = acc[mf][n][r];
    }
  }
}

// ---------------- row softmax: bf16 scores -> bf16 P ----------------
__global__ __launch_bounds__(256) void softmax_k(const bf16* __restrict__ Sm,
                                                 bf16* __restrict__ P, int cols) {
  __shared__ float red[8];
  const long row = blockIdx.x;
  const bf16* sr = Sm + row * (long)cols;
  bf16* pr = P + row * (long)cols;
  const int t = threadIdx.x;
  bf16x8 v = *(const bf16x8*)(sr + t * 8);
  float e[8];
#pragma unroll
  for (int j = 0; j < 8; ++j) e[j] = (float)v[j];
  float m = e[0];
#pragma unroll
  for (int j = 1; j < 8; ++j) m = fmaxf(m, e[j]);
#pragma unroll
  for (int o = 32; o; o >>= 1) m = fmaxf(m, __shfl_xor(m, o));
  if ((t & 63) == 0) red[t >> 6] = m;
  __syncthreads();
  m = fmaxf(fmaxf(red[0], red[1]), fmaxf(red[2], red[3]));
  float s = 0.f;
#pragma unroll
  for (int j = 0; j < 8; ++j) { e[j] = __expf(e[j] - m); s += e[j]; }
#pragma unroll
  for (int o = 32; o; o >>= 1) s += __shfl_xor(s, o);
  if ((t & 63) == 0) red[4 + (t >> 6)] = s;
  __syncthreads();
  s = red[4] + red[5] + red[6] + red[7];
  const float inv = 1.0f / s;
  bf16x8 o8;
#pragma unroll
  for (int j = 0; j < 8; ++j) o8[j] = (bf16)(e[j] * inv);
  *(bf16x8*)(pr + t * 8) = o8;
}

extern "C" void kernel_launch(void* const* d_in, const int* in_sizes, int n_in,
                              void* d_out, int out_size, void* d_ws, size_t ws_size,
                              hipStream_t stream) {
  const float* x  = (const float*)d_in[0];
  const float* Wq = (const float*)d_in[1];
  const float* Wk = (const float*)d_in[2];
  const float* Wv = (const float*)d_in[3];
  float* out = (float*)d_out;

  // workspace (117.44 MB):
  //  [0, 33.55M)        QKbuf bf16 [8192][2048]  -> later P (softmax out)
  //  [33.55M, 50.33M)   Vt bf16 [4][1024][2048]  (written by projT epilogue)
  //  [50.33M, 83.89M)   scores bf16 [4][2048][2048]
  //     (pre-QK this region holds xb @50.33M (16.78M), Wb @67.11M (6.29M))
  char* ws = (char*)d_ws;
  bf16* QKbuf = (bf16*)(ws);
  bf16* P     = (bf16*)(ws);
  bf16* Vt    = (bf16*)(ws + 33554432);
  bf16* scb   = (bf16*)(ws + 50331648);
  bf16* xb    = (bf16*)(ws + 50331648);
  bf16* Wb    = (bf16*)(ws + 67108864);

  dim3 b256(256, 1, 1), b512(512, 1, 1);

  // 1) fused conversion: x -> xb, weights -> Wb packed [3][1024][1024]
  cvt_all<<<2048, b256, 0, stream>>>(x, Wq, Wk, Wv, xb, Wb);

  // 2) transposed QKV proj: C' = Wb·xb^T, 256 blocks exact
  projT<<<dim3(32, 8, 1), b512, 0, stream>>>(Wb, xb, QKbuf, Vt);

  // 3) scores = Q @ K^T / 32 -> bf16 (gemm8; 256 blocks = 1 round)
  gemm8<<<dim3(8, 8, 4), b512, 0, stream>>>(
      QKbuf, QKbuf + 1024, scb, 2048, 2048, 2048,
      4194304, 4194304, 4194304, 1024, 0.03125f);

  // 4) softmax rows (bf16 in) -> bf16 P (overwrites dead QKbuf)
  softmax_k<<<8192, b256, 0, stream>>>(scb, P, 2048);

  // 5) out = P @ Vt^T (gemm2h: 512 blocks = 2/CU)
  gemm2h<<<dim3(8, 16, 4), b256, 0, stream>>>(
      P, Vt, out, 2048, 2048, 1024,
      4194304, 2097152, 2097152, 2048);
}